// Round 6
// baseline (109.629 us; speedup 1.0000x reference)
//
#include <hip/hip_runtime.h>

// WaveletNet lifting: P/U filters are length-1 => scalar multiplies.
// x: (B, L) fp32 -> z: (B, 2, L/2) fp32, plus scalar log_det=0 at out[B*L].
//
// Each thread handles 8 consecutive floats (4 even/odd pairs):
//   2x global_load_dwordx4 in, 2x nontemporal global_store_dwordx4 out.
// Wave-level access: loads cover a contiguous 2 KiB span; each store
// instruction covers a contiguous 1 KiB span. Fully coalesced.
//
// NOTE: __builtin_nontemporal_store requires a clang vector type, not
// HIP_vector_type<float,4> — use ext_vector_type(4) and reinterpret_cast.

#define BB 256
#define LL 65536
#define HH (LL / 2)              // 32768 pairs per row
#define QROW (HH / 4)            // 8192 float4 output chunks per half-row
#define NSTEPS 4

typedef float f32x4 __attribute__((ext_vector_type(4)));

__global__ __launch_bounds__(256) void wavelet_lift_kernel(
    const f32x4* __restrict__ x4,    // B*L/4 vec4s: (e,o,e,o)
    const float* __restrict__ P,     // 4 coeffs (N_STEPS x 1)
    const float* __restrict__ U,     // 4 coeffs
    f32x4* __restrict__ out4,        // B*2*H floats viewed as vec4
    float* __restrict__ out)         // for log_det at [B*L]
{
    const int t = blockIdx.x * blockDim.x + threadIdx.x;  // 0 .. B*L/8-1

    const float p0 = P[0], p1 = P[1], p2 = P[2], p3 = P[3];
    const float u0 = U[0], u1 = U[1], u2 = U[2], u3 = U[3];

    const f32x4 va = x4[2 * t];
    const f32x4 vb = x4[2 * t + 1];

    float e[4] = {va.x, va.z, vb.x, vb.z};
    float o[4] = {va.y, va.w, vb.y, vb.w};

#pragma unroll
    for (int j = 0; j < 4; ++j) {
        float ee = e[j], oo = o[j], d;
        d = oo - p0 * ee; ee = ee + u0 * d; oo = d;
        d = oo - p1 * ee; ee = ee + u1 * d; oo = d;
        d = oo - p2 * ee; ee = ee + u2 * d; oo = d;
        d = oo - p3 * ee; ee = ee + u3 * d; oo = d;
        e[j] = ee; o[j] = oo;
    }

    // Output layout: z[b][0][i] (evens) then z[b][1][i] (odds), H floats each.
    // One row = 2*H floats = 2*H/4 vec4s.
    const int b = t >> 13;               // t / QROW
    const int q = t & (QROW - 1);        // vec4 index within half-row
    f32x4* rowE = out4 + (size_t)b * (2 * HH / 4) + q;
    f32x4* rowO = rowE + QROW;           // + H floats

    f32x4 ve = {e[0], e[1], e[2], e[3]};
    f32x4 vo = {o[0], o[1], o[2], o[3]};
    __builtin_nontemporal_store(ve, rowE);
    __builtin_nontemporal_store(vo, rowO);

    if (t == 0) {
        out[(size_t)BB * LL] = 0.0f;     // log_det
    }
}

extern "C" void kernel_launch(void* const* d_in, const int* in_sizes, int n_in,
                              void* d_out, int out_size, void* d_ws, size_t ws_size,
                              hipStream_t stream) {
    const f32x4* x4 = (const f32x4*)d_in[0];
    const float* P = (const float*)d_in[1];
    const float* U = (const float*)d_in[2];
    f32x4* out4 = (f32x4*)d_out;
    float* out = (float*)d_out;

    const int total_threads = BB * LL / 8;   // 2,097,152
    const int block = 256;
    const int grid = total_threads / block;  // 8192

    wavelet_lift_kernel<<<grid, block, 0, stream>>>(x4, P, U, out4, out);
}